// Round 1
// baseline (685.003 us; speedup 1.0000x reference)
//
#include <hip/hip_runtime.h>
#include <math.h>

// ---------------- problem constants ----------------
constexpr int NPIXC  = 512 * 512;   // pixels per image
constexpr int NCHAN  = 64;          // channels
constexpr int NLAB   = 8;

// K1 tiling
constexpr int NCH     = 16;               // chunks over pixels
constexpr int CHUNKPX = NPIXC / NCH;      // 16384
constexpr int PPHASE  = 128;              // pixels staged per phase
constexpr int NPHASE  = CHUNKPX / PPHASE; // 128
constexpr int XSTR    = 138;              // LDS stride for xs[c][px] (bank-friendly)

constexpr int NITER = 8;                  // Newton-Schulz iterations

// ---------------- workspace layout (float offsets) ----------------
constexpr size_t OFF_MPART = 0;                                   // [2][NCH][8][4096]
constexpr size_t SZ_MPART  = (size_t)2 * NCH * NLAB * 4096;
constexpr size_t OFF_SPART = OFF_MPART + SZ_MPART;                // [2][NCH][8][64]
constexpr size_t SZ_SPART  = (size_t)2 * NCH * NLAB * 64;
constexpr size_t OFF_CNT   = OFF_SPART + SZ_SPART;                // [2][NCH][8]
constexpr size_t SZ_CNT    = (size_t)2 * NCH * NLAB;
constexpr size_t OFF_WH    = OFF_CNT + SZ_CNT;                    // [8][4096]
constexpr size_t OFF_CO    = OFF_WH + (size_t)NLAB * 4096;        // [8][4096]
constexpr size_t OFF_T     = OFF_CO + (size_t)NLAB * 4096;        // [8][4096] row-major T[c][k]
constexpr size_t OFF_MUC   = OFF_T + (size_t)NLAB * 4096;         // [8][64]
constexpr size_t OFF_MUS   = OFF_MUC + (size_t)NLAB * 64;         // [8][64]
constexpr size_t OFF_VALID = OFF_MUS + (size_t)NLAB * 64;         // [8]
// total ~4.45 MB of workspace

// =====================================================================
// K1: per-label counts, channel sums, second moments  M = sum x x^T
// grid (label, chunk, tensor), block 512.  One label per block; pixels
// staged 128 at a time into LDS [c][px]; 8 waves each own an 8x8 tile of
// the 64x64 outer-product accumulator and split the pixel list mod 8.
// =====================================================================
__global__ __launch_bounds__(512) void k_moments(
    const float* __restrict__ cont, const float* __restrict__ styl,
    const int* __restrict__ cseg, const int* __restrict__ sseg,
    float* __restrict__ ws)
{
  const int l  = blockIdx.x;
  const int ch = blockIdx.y;
  const int t  = blockIdx.z;
  const float* __restrict__ X = t ? styl : cont;
  const int* __restrict__ seg = t ? sseg : cseg;

  const int tid  = threadIdx.x;
  const int lane = tid & 63;
  const int wv   = tid >> 6;          // 0..7

  __shared__ float xs[NCHAN * XSTR];  // 35.3 KB, [c][px] stride 138
  __shared__ int   labv[PPHASE];
  __shared__ float red2[8][64];
  __shared__ float redc[8];

  const int r0 = (lane >> 3) << 3;    // tile rows
  const int c0 = (lane & 7) << 3;     // tile cols

  float acc[8][8];
  #pragma unroll
  for (int i = 0; i < 8; ++i)
    #pragma unroll
    for (int j = 0; j < 8; ++j) acc[i][j] = 0.f;

  float ssum = 0.f;   // per-thread partial of channel 'lane' sum
  int   cnt  = 0;

  const int pbase = ch * CHUNKPX;
  for (int ph = 0; ph < NPHASE; ++ph) {
    const int p0 = pbase + ph * PPHASE;
    if (tid < PPHASE) labv[tid] = seg[p0 + tid];
    // stage 64ch x 128px, float2 per lane (coalesced 512B/wave)
    #pragma unroll
    for (int r = 0; r < 8; ++r) {
      const int c = r * 8 + wv;
      const float2 v = *reinterpret_cast<const float2*>(&X[(size_t)c * NPIXC + p0 + 2 * lane]);
      *reinterpret_cast<float2*>(&xs[c * XSTR + 2 * lane]) = v;
    }
    __syncthreads();
    for (int j = wv; j < PPHASE; j += 8) {
      if (labv[j] != l) continue;     // wave-uniform skip
      float av[8], bv[8];
      #pragma unroll
      for (int i = 0; i < 8; ++i) av[i] = xs[(r0 + i) * XSTR + j];
      #pragma unroll
      for (int i = 0; i < 8; ++i) bv[i] = xs[(c0 + i) * XSTR + j];
      #pragma unroll
      for (int i = 0; i < 8; ++i)
        #pragma unroll
        for (int jj = 0; jj < 8; ++jj) acc[i][jj] += av[i] * bv[jj];
      ssum += xs[lane * XSTR + j];
      ++cnt;
    }
    __syncthreads();
  }

  // flush: reduce 8 wave-partials via LDS (reuse xs), 4 row-stages of 16 rows
  float* red = xs;  // 8*1024 floats needed <= 64*138
  float* Mdst = ws + OFF_MPART + (size_t)((t * NCH + ch) * NLAB + l) * 4096;
  #pragma unroll
  for (int s = 0; s < 4; ++s) {
    if ((lane >> 4) == s) {
      #pragma unroll
      for (int i = 0; i < 8; ++i)
        #pragma unroll
        for (int jj = 0; jj < 8; ++jj)
          red[wv * 1024 + (r0 - 16 * s + i) * 64 + (c0 + jj)] = acc[i][jj];
    }
    __syncthreads();
    {
      float2 s01 = make_float2(0.f, 0.f);
      #pragma unroll
      for (int w = 0; w < 8; ++w) {
        const float2 v = *reinterpret_cast<const float2*>(&red[w * 1024 + tid * 2]);
        s01.x += v.x; s01.y += v.y;
      }
      *reinterpret_cast<float2*>(&Mdst[s * 1024 + tid * 2]) = s01;
    }
    __syncthreads();
  }
  red2[wv][lane] = ssum;
  if (lane == 0) redc[wv] = (float)cnt;
  __syncthreads();
  if (tid < 64) {
    float s = 0.f;
    #pragma unroll
    for (int w = 0; w < 8; ++w) s += red2[w][tid];
    ws[OFF_SPART + (size_t)((t * NCH + ch) * NLAB + l) * 64 + tid] = s;
  }
  if (tid == 0) {
    float c = 0.f;
    #pragma unroll
    for (int w = 0; w < 8; ++w) c += redc[w];
    ws[OFF_CNT + (size_t)(t * NCH + ch) * NLAB + l] = c;
  }
}

// =====================================================================
// 64x64 matmul on LDS, operands assumed symmetric (stored ~= transpose).
// A-operand read A[k*64+r]: lane-contiguous (2-way, free).
// B-operand read as wave-uniform float4 broadcasts.
// dst written transposed (conflict-free b32 stores); dst stays ~symmetric
// because all NS operands commute (polynomials of the same matrix).
// dst = p1*(A@B) + p0*I
// =====================================================================
__device__ __forceinline__ void mm64s(float* __restrict__ dst,
    const float* __restrict__ A, const float* __restrict__ B,
    int tid, float p0, float p1)
{
  const int r  = tid & 63;
  const int cb = (tid >> 6) << 4;
  float acc[16];
  #pragma unroll
  for (int j = 0; j < 16; ++j) acc[j] = 0.f;
  #pragma unroll 8
  for (int k = 0; k < 64; ++k) {
    const float a = A[k * 64 + r];
    const float4 b0 = *reinterpret_cast<const float4*>(&B[k * 64 + cb + 0]);
    const float4 b1 = *reinterpret_cast<const float4*>(&B[k * 64 + cb + 4]);
    const float4 b2 = *reinterpret_cast<const float4*>(&B[k * 64 + cb + 8]);
    const float4 b3 = *reinterpret_cast<const float4*>(&B[k * 64 + cb + 12]);
    acc[ 0] += a * b0.x; acc[ 1] += a * b0.y; acc[ 2] += a * b0.z; acc[ 3] += a * b0.w;
    acc[ 4] += a * b1.x; acc[ 5] += a * b1.y; acc[ 6] += a * b1.z; acc[ 7] += a * b1.w;
    acc[ 8] += a * b2.x; acc[ 9] += a * b2.y; acc[10] += a * b2.z; acc[11] += a * b2.w;
    acc[12] += a * b3.x; acc[13] += a * b3.y; acc[14] += a * b3.z; acc[15] += a * b3.w;
  }
  #pragma unroll
  for (int j = 0; j < 16; ++j) {
    const int col = cb + j;
    dst[col * 64 + r] = p1 * acc[j] + ((r == col) ? p0 : 0.f);
  }
}

// =====================================================================
// K2a: build covariance, coupled Newton-Schulz for A^{+-1/2}.
// grid 16: blockIdx = t*8 + l.  t=0 -> WH = cov_c^{-1/2}; t=1 -> CO = cov_s^{1/2}
// =====================================================================
__global__ __launch_bounds__(256) void k_ns(float* __restrict__ ws)
{
  const int l   = blockIdx.x & 7;
  const int t   = blockIdx.x >> 3;
  const int tid = threadIdx.x;
  __shared__ float bA[4096], bY[4096], bZ[4096], bT[4096];  // exactly 64 KB

  float n0 = 0.f, n1 = 0.f;
  for (int chk = 0; chk < NCH; ++chk) {
    n0 += ws[OFF_CNT + (size_t)chk * NLAB + l];
    n1 += ws[OFF_CNT + (size_t)(NCH + chk) * NLAB + l];
  }
  const float n = t ? n1 : n0;
  const bool valid = (n0 > 10.f) && (n1 > 10.f) && (n0 < 100.f * n1) && (n1 < 100.f * n0);

  if (tid < 64) {   // S reduce into bY[0..63]
    float s = 0.f;
    for (int chk = 0; chk < NCH; ++chk)
      s += ws[OFF_SPART + (size_t)((t * NCH + chk) * NLAB + l) * 64 + tid];
    bY[tid] = s;
  }
  __syncthreads();

  const float invn = 1.f / fmaxf(n, 1.f);
  const float nm1  = n - 1.f;
  const float dv   = (nm1 == 0.f) ? 1e-5f : nm1;   // matches jnp.where(n-1==0, EPS, n-1)
  const float rdiv = 1.f / dv;

  const int i0 = tid >> 2;
  const int jb = (tid & 3) << 4;
  {
    const float Si = bY[i0];
    #pragma unroll
    for (int q = 0; q < 4; ++q) {
      const int j = jb + 4 * q;
      float4 m = make_float4(0.f, 0.f, 0.f, 0.f);
      for (int chk = 0; chk < NCH; ++chk) {
        const float4 v = *reinterpret_cast<const float4*>(
            &ws[OFF_MPART + (size_t)((t * NCH + chk) * NLAB + l) * 4096 + i0 * 64 + j]);
        m.x += v.x; m.y += v.y; m.z += v.z; m.w += v.w;
      }
      const float4 Sj = *reinterpret_cast<const float4*>(&bY[j]);
      float4 a;
      a.x = (m.x - Si * Sj.x * invn) * rdiv + ((t == 0 && i0 == j + 0) ? 1.f : 0.f);
      a.y = (m.y - Si * Sj.y * invn) * rdiv + ((t == 0 && i0 == j + 1) ? 1.f : 0.f);
      a.z = (m.z - Si * Sj.z * invn) * rdiv + ((t == 0 && i0 == j + 2) ? 1.f : 0.f);
      a.w = (m.w - Si * Sj.w * invn) * rdiv + ((t == 0 && i0 == j + 3) ? 1.f : 0.f);
      *reinterpret_cast<float4*>(&bA[i0 * 64 + j]) = a;
    }
  }
  __syncthreads();

  if (tid < 64)
    ws[(t ? OFF_MUS : OFF_MUC) + (size_t)l * 64 + tid] = bY[tid] * invn;
  if (t == 0 && tid == 0) ws[OFF_VALID + l] = valid ? 1.f : 0.f;

  if (tid < 64) {   // Gershgorin row sums
    float s = 0.f;
    for (int j = 0; j < 64; ++j) s += fabsf(bA[tid * 64 + j]);
    bZ[tid] = s;
  }
  __syncthreads();
  if (tid == 0) {
    float c = 0.f;
    for (int i = 0; i < 64; ++i) c = fmaxf(c, bZ[i]);
    bT[0] = c;
  }
  __syncthreads();
  const float cval = bT[0];
  const float rc   = 1.f / cval;
  __syncthreads();

  // init Y = A/c, Z = I
  #pragma unroll
  for (int q = 0; q < 4; ++q) {
    const int j = jb + 4 * q;
    const float4 a = *reinterpret_cast<const float4*>(&bA[i0 * 64 + j]);
    float4 y; y.x = a.x * rc; y.y = a.y * rc; y.z = a.z * rc; y.w = a.w * rc;
    *reinterpret_cast<float4*>(&bY[i0 * 64 + j]) = y;
    float4 z;
    z.x = (i0 == j + 0) ? 1.f : 0.f; z.y = (i0 == j + 1) ? 1.f : 0.f;
    z.z = (i0 == j + 2) ? 1.f : 0.f; z.w = (i0 == j + 3) ? 1.f : 0.f;
    *reinterpret_cast<float4*>(&bZ[i0 * 64 + j]) = z;
  }
  __syncthreads();

  float *Y = bY, *Z = bZ, *T = bT, *W = bA;
  for (int it = 0; it < NITER; ++it) {
    mm64s(T, Z, Y, tid, 1.5f, -0.5f); __syncthreads();   // T = 1.5I - 0.5 Z@Y
    mm64s(W, Y, T, tid, 0.f, 1.f);    __syncthreads();   // newY = Y@T
    mm64s(Y, T, Z, tid, 0.f, 1.f);    __syncthreads();   // newZ = T@Z (into old Y buf)
    float* nz = Y; Y = W; W = Z; Z = nz;
  }

  const float osc = t ? sqrtf(cval) : rsqrtf(cval);
  const float* src = t ? Y : Z;
  float* dst = ws + (t ? OFF_CO : OFF_WH) + (size_t)l * 4096;
  #pragma unroll
  for (int q = 0; q < 4; ++q) {
    const int j = jb + 4 * q;
    float4 v = *reinterpret_cast<const float4*>(&src[i0 * 64 + j]);
    v.x *= osc; v.y *= osc; v.z *= osc; v.w *= osc;
    *reinterpret_cast<float4*>(&dst[i0 * 64 + j]) = v;
  }
}

// =====================================================================
// K2b: T_l = CO_l @ WH_l  (not symmetric -> store true row-major to global)
// =====================================================================
__global__ __launch_bounds__(256) void k_tmat(float* __restrict__ ws)
{
  const int l   = blockIdx.x;
  const int tid = threadIdx.x;
  __shared__ float Am[4096], Bm[4096];
  #pragma unroll
  for (int q = 0; q < 4; ++q) {
    const int e = tid * 16 + q * 4;
    *reinterpret_cast<float4*>(&Am[e]) =
        *reinterpret_cast<const float4*>(&ws[OFF_CO + (size_t)l * 4096 + e]);
    *reinterpret_cast<float4*>(&Bm[e]) =
        *reinterpret_cast<const float4*>(&ws[OFF_WH + (size_t)l * 4096 + e]);
  }
  __syncthreads();
  const int r  = tid & 63;
  const int cb = (tid >> 6) << 4;
  float acc[16];
  #pragma unroll
  for (int j = 0; j < 16; ++j) acc[j] = 0.f;
  #pragma unroll 8
  for (int k = 0; k < 64; ++k) {
    const float a = Am[k * 64 + r];   // == CO[r][k] (symmetric)
    const float4 b0 = *reinterpret_cast<const float4*>(&Bm[k * 64 + cb + 0]);
    const float4 b1 = *reinterpret_cast<const float4*>(&Bm[k * 64 + cb + 4]);
    const float4 b2 = *reinterpret_cast<const float4*>(&Bm[k * 64 + cb + 8]);
    const float4 b3 = *reinterpret_cast<const float4*>(&Bm[k * 64 + cb + 12]);
    acc[ 0] += a * b0.x; acc[ 1] += a * b0.y; acc[ 2] += a * b0.z; acc[ 3] += a * b0.w;
    acc[ 4] += a * b1.x; acc[ 5] += a * b1.y; acc[ 6] += a * b1.z; acc[ 7] += a * b1.w;
    acc[ 8] += a * b2.x; acc[ 9] += a * b2.y; acc[10] += a * b2.z; acc[11] += a * b2.w;
    acc[12] += a * b3.x; acc[13] += a * b3.y; acc[14] += a * b3.z; acc[15] += a * b3.w;
  }
  #pragma unroll
  for (int j = 0; j < 16; ++j)
    ws[OFF_T + (size_t)l * 4096 + r * 64 + cb + j] = acc[j];
}

// =====================================================================
// K3: apply. Each thread owns one pixel: xm[64] in VGPRs, T staged in
// LDS per 16-row quarter (8 labels, padded for bank spread), coalesced IO.
// =====================================================================
__global__ __launch_bounds__(256) void k_apply(
    const float* __restrict__ cont, const int* __restrict__ cseg,
    const float* __restrict__ ws, float* __restrict__ out)
{
  const int tid = threadIdx.x;
  const int p   = blockIdx.x * 256 + tid;
  __shared__ float Tq[8 * 1028];            // quarter of each label's T
  __shared__ float muc[8 * 68], mus[8 * 68];
  __shared__ float validf[8];

  for (int e = tid; e < 512; e += 256) {
    muc[(e >> 6) * 68 + (e & 63)] = ws[OFF_MUC + e];
    mus[(e >> 6) * 68 + (e & 63)] = ws[OFF_MUS + e];
  }
  if (tid < 8) validf[tid] = ws[OFF_VALID + tid];
  __syncthreads();

  const int  lab = cseg[p];
  const bool v   = validf[lab] > 0.5f;

  float xm[64];
  #pragma unroll
  for (int k = 0; k < 64; ++k)
    xm[k] = cont[(size_t)k * NPIXC + p] - muc[lab * 68 + k];

  for (int q = 0; q < 4; ++q) {
    __syncthreads();
    #pragma unroll
    for (int r = 0; r < 8; ++r) {
      const int fi = r * 256 + tid;
      *reinterpret_cast<float4*>(&Tq[(fi >> 8) * 1028 + (fi & 255) * 4]) =
          *reinterpret_cast<const float4*>(
              &ws[OFF_T + (size_t)(fi >> 8) * 4096 + q * 1024 + (fi & 255) * 4]);
    }
    __syncthreads();
    for (int c = 0; c < 16; ++c) {
      float a0 = 0.f, a1 = 0.f, a2 = 0.f, a3 = 0.f;
      const float* Trow = &Tq[lab * 1028 + c * 64];
      #pragma unroll
      for (int kq = 0; kq < 16; ++kq) {
        const float4 tv = *reinterpret_cast<const float4*>(&Trow[4 * kq]);
        a0 += tv.x * xm[4 * kq + 0];
        a1 += tv.y * xm[4 * kq + 1];
        a2 += tv.z * xm[4 * kq + 2];
        a3 += tv.w * xm[4 * kq + 3];
      }
      const int   oc  = q * 16 + c;
      const float acc = (a0 + a1) + (a2 + a3);
      const float xv  = cont[(size_t)oc * NPIXC + p];   // pristine for invalid labels
      out[(size_t)oc * NPIXC + p] = v ? (acc + mus[lab * 68 + oc]) : xv;
    }
  }
}

// =====================================================================
extern "C" void kernel_launch(void* const* d_in, const int* in_sizes, int n_in,
                              void* d_out, int out_size, void* d_ws, size_t ws_size,
                              hipStream_t stream)
{
  const float* cont = (const float*)d_in[0];
  const float* styl = (const float*)d_in[1];
  const int*   cseg = (const int*)d_in[2];
  const int*   sseg = (const int*)d_in[3];
  float*       ws   = (float*)d_ws;
  float*       out  = (float*)d_out;

  dim3 g1(NLAB, NCH, 2);
  k_moments<<<g1, 512, 0, stream>>>(cont, styl, cseg, sseg, ws);
  k_ns<<<dim3(16), 256, 0, stream>>>(ws);
  k_tmat<<<dim3(8), 256, 0, stream>>>(ws);
  k_apply<<<dim3(NPIXC / 256), 256, 0, stream>>>(cont, cseg, ws, out);
}

// Round 2
// 457.285 us; speedup vs baseline: 1.4980x; 1.4980x over previous
//
#include <hip/hip_runtime.h>
#include <math.h>

constexpr int NPIX  = 262144;   // 512*512
constexpr int NLAB  = 8;
constexpr int NITER = 5;        // Newton-Schulz iterations (e0<=0.6 -> e5 < 1e-10)

// ---------------- workspace layout (float offsets), runtime nblk ----------------
__host__ __device__ inline size_t offMpart()         { return 0; }
__host__ __device__ inline size_t offSpart(int nblk) { return (size_t)2*nblk*8*4096; }
__host__ __device__ inline size_t offCnt(int nblk)   { return offSpart(nblk) + (size_t)2*nblk*8*64; }
__host__ __device__ inline size_t offMR(int nblk)    { return offCnt(nblk) + (size_t)2*nblk*8; }
__host__ __device__ inline size_t offSR(int nblk)    { return offMR(nblk) + 2*8*4096; }
__host__ __device__ inline size_t offCR(int nblk)    { return offSR(nblk) + 2*8*64; }
__host__ __device__ inline size_t offWH(int nblk)    { return offCR(nblk) + 16; }
__host__ __device__ inline size_t offCO(int nblk)    { return offWH(nblk) + 8*4096; }
__host__ __device__ inline size_t offT(int nblk)     { return offCO(nblk) + 8*4096; }
__host__ __device__ inline size_t offBIAS(int nblk)  { return offT(nblk) + 8*4096; }
__host__ __device__ inline size_t offMUC(int nblk)   { return offBIAS(nblk) + 8*64; }
__host__ __device__ inline size_t offMUS(int nblk)   { return offMUC(nblk) + 8*64; }
__host__ __device__ inline size_t offVALID(int nblk) { return offMUS(nblk) + 8*64; }

// =====================================================================
// K1: single-pass per-label moments. grid (nblk, 2 tensors), block 512.
// 8 waves/block; wave w owns label w's 64x64 accumulator (8x8/lane).
// Pixels staged 256/phase into xs[px][64] with XOR-4 column swizzle so
// staging writes are 4-way and compute b128 reads are 2-way (free).
// =====================================================================
__global__ __launch_bounds__(512, 2) void k_moments(
    const float* __restrict__ cont, const float* __restrict__ styl,
    const int* __restrict__ cseg, const int* __restrict__ sseg,
    float* __restrict__ ws, int nblk)
{
  const int t = blockIdx.y, blk = blockIdx.x;
  const float* __restrict__ X  = t ? styl : cont;
  const int*  __restrict__ seg = t ? sseg : cseg;
  const int tid = threadIdx.x, lane = tid & 63, wv = tid >> 6;

  __shared__ float xs[256 * 64];   // exactly 64 KB

  const int r0 = (lane >> 3) << 3;
  const int c0 = (lane & 7) << 3;

  float acc[8][8];
  #pragma unroll
  for (int i = 0; i < 8; ++i)
    #pragma unroll
    for (int j = 0; j < 8; ++j) acc[i][j] = 0.f;
  float ssum = 0.f;
  int   cnt  = 0;

  const int chunk = NPIX / nblk;
  const int pbase = blk * chunk;
  const int nph   = chunk >> 8;
  const int ci  = tid >> 5;             // 0..15
  const int pxi = (tid & 31) << 2;      // 0..124
  const int swW = (tid & 7) << 2;       // staging column swizzle (bits 2..4)

  for (int ph = 0; ph < nph; ++ph) {
    const int p0 = pbase + (ph << 8);
    float4 v[8];
    #pragma unroll
    for (int q = 0; q < 8; ++q) {
      const int c  = ci + ((q & 3) << 4);
      const int px = pxi + ((q >> 2) << 7);
      v[q] = *reinterpret_cast<const float4*>(&X[(size_t)c * NPIX + p0 + px]);
    }
    int lb[4];
    #pragma unroll
    for (int g = 0; g < 4; ++g) lb[g] = seg[p0 + (g << 6) + lane];

    __syncthreads();   // previous phase reads done
    #pragma unroll
    for (int q = 0; q < 8; ++q) {
      const int c  = ci + ((q & 3) << 4);
      const int px = pxi + ((q >> 2) << 7);
      const int pc = c ^ swW;
      xs[(px + 0) * 64 + pc] = v[q].x;
      xs[(px + 1) * 64 + pc] = v[q].y;
      xs[(px + 2) * 64 + pc] = v[q].z;
      xs[(px + 3) * 64 + pc] = v[q].w;
    }
    __syncthreads();   // staging visible

    for (int g = 0; g < 4; ++g) {
      unsigned long long m = __ballot(lb[g] == wv);
      cnt += __popcll(m);
      while (m) {
        const int j = (g << 6) + __builtin_ctzll(m);
        m &= m - 1;
        const int sw = j & 28;           // ((j>>2)&7)<<2
        const float4 a0 = *reinterpret_cast<const float4*>(&xs[j * 64 + (r0 ^ sw)]);
        const float4 a1 = *reinterpret_cast<const float4*>(&xs[j * 64 + ((r0 ^ sw) ^ 4)]);
        const float4 b0 = *reinterpret_cast<const float4*>(&xs[j * 64 + (c0 ^ sw)]);
        const float4 b1 = *reinterpret_cast<const float4*>(&xs[j * 64 + ((c0 ^ sw) ^ 4)]);
        ssum += xs[j * 64 + (lane ^ sw)];
        const float av[8] = {a0.x, a0.y, a0.z, a0.w, a1.x, a1.y, a1.z, a1.w};
        const float bv[8] = {b0.x, b0.y, b0.z, b0.w, b1.x, b1.y, b1.z, b1.w};
        #pragma unroll
        for (int i = 0; i < 8; ++i)
          #pragma unroll
          for (int jj = 0; jj < 8; ++jj) acc[i][jj] += av[i] * bv[jj];
      }
    }
  }

  // flush partials (logical indexing)
  float* Md = ws + offMpart() + (size_t)((t * nblk + blk) * 8 + wv) * 4096;
  #pragma unroll
  for (int i = 0; i < 8; ++i) {
    *reinterpret_cast<float4*>(&Md[(r0 + i) * 64 + c0]) =
        make_float4(acc[i][0], acc[i][1], acc[i][2], acc[i][3]);
    *reinterpret_cast<float4*>(&Md[(r0 + i) * 64 + c0 + 4]) =
        make_float4(acc[i][4], acc[i][5], acc[i][6], acc[i][7]);
  }
  ws[offSpart(nblk) + (size_t)((t * nblk + blk) * 8 + wv) * 64 + lane] = ssum;
  if (lane == 0) ws[offCnt(nblk) + (size_t)(t * nblk + blk) * 8 + wv] = (float)cnt;
}

// =====================================================================
// K1b: reduce partials over nblk. grid 2*8*16 = 256 blocks, 256 threads.
// =====================================================================
__global__ __launch_bounds__(256) void k_reduce(float* __restrict__ ws, int nblk)
{
  const int b = blockIdx.x;
  const int sgm = b & 15, tl = b >> 4, l = tl & 7, t = tl >> 3;
  const int tid = threadIdx.x;
  const size_t stride = (size_t)8 * 4096;
  const float* src = ws + offMpart() + (size_t)(t * nblk) * stride + (size_t)l * 4096 + sgm * 256 + tid;
  float s = 0.f;
  for (int bb = 0; bb < nblk; ++bb) s += src[bb * stride];
  ws[offMR(nblk) + (size_t)tl * 4096 + sgm * 256 + tid] = s;
  if (sgm == 0) {
    if (tid < 64) {
      float q = 0.f;
      for (int bb = 0; bb < nblk; ++bb)
        q += ws[offSpart(nblk) + (size_t)((t * nblk + bb) * 8 + l) * 64 + tid];
      ws[offSR(nblk) + tl * 64 + tid] = q;
    } else if (tid == 64) {
      float q = 0.f;
      for (int bb = 0; bb < nblk; ++bb)
        q += ws[offCnt(nblk) + (size_t)(t * nblk + bb) * 8 + l];
      ws[offCR(nblk) + tl] = q;
    }
  }
}

// =====================================================================
// 64x64 matmul, operands symmetric (A[r][k] read as A[k][r], row-k b128).
// Block 256: wave w owns rows [16w,16w+16), lane tile 4x4.
// Per k per wave: 2 conflict-free ds_read_b128 + 16 FMA.
// dst = p1*(A@B) + p0*I, written row-major.
// =====================================================================
__device__ __forceinline__ void mm64s4(float* __restrict__ dst,
    const float* __restrict__ A, const float* __restrict__ B,
    int tid, float p0, float p1)
{
  const int lane = tid & 63, wv = tid >> 6;
  const int r0 = (wv << 4) + ((lane >> 4) << 2);
  const int c0 = (lane & 15) << 2;
  float acc[4][4];
  #pragma unroll
  for (int i = 0; i < 4; ++i)
    #pragma unroll
    for (int j = 0; j < 4; ++j) acc[i][j] = 0.f;
  #pragma unroll 4
  for (int k = 0; k < 64; ++k) {
    const float4 a = *reinterpret_cast<const float4*>(&A[k * 64 + r0]);
    const float4 b = *reinterpret_cast<const float4*>(&B[k * 64 + c0]);
    const float av[4] = {a.x, a.y, a.z, a.w};
    const float bv[4] = {b.x, b.y, b.z, b.w};
    #pragma unroll
    for (int i = 0; i < 4; ++i)
      #pragma unroll
      for (int j = 0; j < 4; ++j) acc[i][j] += av[i] * bv[j];
  }
  #pragma unroll
  for (int i = 0; i < 4; ++i) {
    float4 o;
    o.x = p1 * acc[i][0] + (((r0 + i) == (c0 + 0)) ? p0 : 0.f);
    o.y = p1 * acc[i][1] + (((r0 + i) == (c0 + 1)) ? p0 : 0.f);
    o.z = p1 * acc[i][2] + (((r0 + i) == (c0 + 2)) ? p0 : 0.f);
    o.w = p1 * acc[i][3] + (((r0 + i) == (c0 + 3)) ? p0 : 0.f);
    *reinterpret_cast<float4*>(&dst[(r0 + i) * 64 + c0]) = o;
  }
}

// =====================================================================
// K2: cov build + coupled Newton-Schulz. grid 16 (t*8+l), block 256.
// t=0: WH = (cov_c+I)^-1/2 ; t=1: CO = cov_s^1/2
// =====================================================================
__global__ __launch_bounds__(256) void k_ns(float* __restrict__ ws, int nblk)
{
  const int l = blockIdx.x & 7, t = blockIdx.x >> 3;
  const int tid = threadIdx.x;
  __shared__ float bA[4096], bY[4096], bZ[4096], bT[4096];  // exactly 64 KB
  float* svec   = bT;        // scratch aliases, consumed before chain starts
  float* rowsum = bT + 64;
  float* scal   = bT + 128;

  const float n0 = ws[offCR(nblk) + l];
  const float n1 = ws[offCR(nblk) + 8 + l];
  const float n = t ? n1 : n0;
  const bool valid = (n0 > 10.f) && (n1 > 10.f) && (n0 < 100.f * n1) && (n1 < 100.f * n0);
  if (tid < 64) svec[tid] = ws[offSR(nblk) + (t * 8 + l) * 64 + tid];
  __syncthreads();

  const float invn = 1.f / fmaxf(n, 1.f);
  const float nm1  = n - 1.f;
  const float rdiv = 1.f / ((nm1 == 0.f) ? 1e-5f : nm1);
  const int i0 = tid >> 2, jb = (tid & 3) << 4;
  const float Si = svec[i0];
  const float* MRp = ws + offMR(nblk) + (size_t)(t * 8 + l) * 4096;
  #pragma unroll
  for (int q = 0; q < 4; ++q) {
    const int j = jb + (q << 2);
    const float4 m  = *reinterpret_cast<const float4*>(&MRp[i0 * 64 + j]);
    const float4 sj = *reinterpret_cast<const float4*>(&svec[j]);
    float4 a;
    a.x = (m.x - Si * sj.x * invn) * rdiv + ((t == 0 && i0 == j + 0) ? 1.f : 0.f);
    a.y = (m.y - Si * sj.y * invn) * rdiv + ((t == 0 && i0 == j + 1) ? 1.f : 0.f);
    a.z = (m.z - Si * sj.z * invn) * rdiv + ((t == 0 && i0 == j + 2) ? 1.f : 0.f);
    a.w = (m.w - Si * sj.w * invn) * rdiv + ((t == 0 && i0 == j + 3) ? 1.f : 0.f);
    *reinterpret_cast<float4*>(&bA[i0 * 64 + j]) = a;
  }
  if (tid < 64) ws[(t ? offMUS(nblk) : offMUC(nblk)) + l * 64 + tid] = svec[tid] * invn;
  if (t == 0 && tid == 0) ws[offVALID(nblk) + l] = valid ? 1.f : 0.f;
  __syncthreads();

  if (tid < 64) {   // Gershgorin row sums (column read, bA exactly symmetric)
    float s = 0.f;
    for (int j = 0; j < 64; ++j) s += fabsf(bA[j * 64 + tid]);
    rowsum[tid] = s;
  }
  __syncthreads();
  if (tid == 0) {
    float c = 0.f;
    for (int i = 0; i < 64; ++i) c = fmaxf(c, rowsum[i]);
    scal[0] = fmaxf(c, 1e-20f);
  }
  __syncthreads();
  const float cval = scal[0];
  const float rc = 1.f / cval;
  __syncthreads();

  #pragma unroll
  for (int q = 0; q < 4; ++q) {   // Y = A/c, Z = I
    const int j = jb + (q << 2);
    float4 a = *reinterpret_cast<const float4*>(&bA[i0 * 64 + j]);
    a.x *= rc; a.y *= rc; a.z *= rc; a.w *= rc;
    *reinterpret_cast<float4*>(&bY[i0 * 64 + j]) = a;
    float4 z;
    z.x = (i0 == j + 0) ? 1.f : 0.f; z.y = (i0 == j + 1) ? 1.f : 0.f;
    z.z = (i0 == j + 2) ? 1.f : 0.f; z.w = (i0 == j + 3) ? 1.f : 0.f;
    *reinterpret_cast<float4*>(&bZ[i0 * 64 + j]) = z;
  }
  __syncthreads();

  float *Y = bY, *Z = bZ, *T = bT, *Wb = bA;
  for (int it = 0; it < NITER; ++it) {
    mm64s4(T, Z, Y, tid, 1.5f, -0.5f); __syncthreads();
    mm64s4(Wb, Y, T, tid, 0.f, 1.f);   __syncthreads();
    mm64s4(Y, T, Z, tid, 0.f, 1.f);    __syncthreads();
    float* nz = Y; Y = Wb; Wb = Z; Z = nz;
  }

  const float osc = t ? sqrtf(cval) : (1.0f / sqrtf(cval));
  const float* src = t ? Y : Z;
  float* dst = ws + (t ? offCO(nblk) : offWH(nblk)) + (size_t)l * 4096;
  #pragma unroll
  for (int q = 0; q < 4; ++q) {
    const int j = jb + (q << 2);
    float4 v = *reinterpret_cast<const float4*>(&src[i0 * 64 + j]);
    v.x *= osc; v.y *= osc; v.z *= osc; v.w *= osc;
    *reinterpret_cast<float4*>(&dst[i0 * 64 + j]) = v;
  }
}

// =====================================================================
// K2b: T_l = CO_l @ WH_l (identity if invalid), bias_l = mus - T@muc (0 if invalid)
// =====================================================================
__global__ __launch_bounds__(256) void k_tmat(float* __restrict__ ws, int nblk)
{
  const int l = blockIdx.x;
  const int tid = threadIdx.x;
  __shared__ float Am[4096], Bm[4096];
  __shared__ float red[64];
  __shared__ float mucS[64], musS[64];
  const bool valid = ws[offVALID(nblk) + l] > 0.5f;
  if (tid < 64) {
    red[tid] = 0.f;
    mucS[tid] = ws[offMUC(nblk) + l * 64 + tid];
    musS[tid] = ws[offMUS(nblk) + l * 64 + tid];
  }
  #pragma unroll
  for (int q = 0; q < 4; ++q) {
    const int e = tid * 4 + q * 1024;
    *reinterpret_cast<float4*>(&Am[e]) =
        *reinterpret_cast<const float4*>(&ws[offCO(nblk) + (size_t)l * 4096 + e]);
    *reinterpret_cast<float4*>(&Bm[e]) =
        *reinterpret_cast<const float4*>(&ws[offWH(nblk) + (size_t)l * 4096 + e]);
  }
  __syncthreads();
  const int lane = tid & 63, wv = tid >> 6;
  const int r0 = (wv << 4) + ((lane >> 4) << 2);
  const int c0 = (lane & 15) << 2;
  float acc[4][4];
  #pragma unroll
  for (int i = 0; i < 4; ++i)
    #pragma unroll
    for (int j = 0; j < 4; ++j) acc[i][j] = 0.f;
  #pragma unroll 4
  for (int k = 0; k < 64; ++k) {
    const float4 a = *reinterpret_cast<const float4*>(&Am[k * 64 + r0]);  // CO symmetric
    const float4 b = *reinterpret_cast<const float4*>(&Bm[k * 64 + c0]);
    const float av[4] = {a.x, a.y, a.z, a.w};
    const float bv[4] = {b.x, b.y, b.z, b.w};
    #pragma unroll
    for (int i = 0; i < 4; ++i)
      #pragma unroll
      for (int j = 0; j < 4; ++j) acc[i][j] += av[i] * bv[j];
  }
  float* Td = ws + offT(nblk) + (size_t)l * 4096;
  #pragma unroll
  for (int i = 0; i < 4; ++i) {
    float4 o;
    o.x = valid ? acc[i][0] : (((r0 + i) == (c0 + 0)) ? 1.f : 0.f);
    o.y = valid ? acc[i][1] : (((r0 + i) == (c0 + 1)) ? 1.f : 0.f);
    o.z = valid ? acc[i][2] : (((r0 + i) == (c0 + 2)) ? 1.f : 0.f);
    o.w = valid ? acc[i][3] : (((r0 + i) == (c0 + 3)) ? 1.f : 0.f);
    *reinterpret_cast<float4*>(&Td[(r0 + i) * 64 + c0]) = o;
    const float bp = o.x * mucS[c0] + o.y * mucS[c0 + 1] + o.z * mucS[c0 + 2] + o.w * mucS[c0 + 3];
    atomicAdd(&red[r0 + i], bp);
  }
  __syncthreads();
  if (tid < 64) ws[offBIAS(nblk) + l * 64 + tid] = valid ? (musS[tid] - red[tid]) : 0.f;
}

// =====================================================================
// K3: apply y = T_lab x + bias_lab. 1008-px windows, block 512.
// Block-local counting sort by label; 2 same-label pixels per thread so
// each T-row b128 read feeds 8 FMAs. Invalid labels pass through exactly
// via T=I/bias=0. Pairs <= 504+4 <= 512 always.
// =====================================================================
__global__ __launch_bounds__(512, 2) void k_apply(
    const float* __restrict__ cont, const int* __restrict__ cseg,
    const float* __restrict__ ws, float* __restrict__ out, int nblk)
{
  const int tid = threadIdx.x;
  const int base = blockIdx.x * 1008;
  const int W = min(1008, NPIX - base);
  __shared__ float Tq[8 * 1028];
  __shared__ float biasS[8 * 66];
  __shared__ int labw[1008];
  __shared__ unsigned short sidx[1016];
  __shared__ int cnt8[8], cur8[8], offs8[8], npS;

  if (tid < 8) cnt8[tid] = 0;
  if (tid < 512) biasS[(tid >> 6) * 66 + (tid & 63)] = ws[offBIAS(nblk) + tid];
  __syncthreads();
  for (int i = tid; i < W; i += 512) {
    const int lb = cseg[base + i];
    labw[i] = lb;
    atomicAdd(&cnt8[lb], 1);
  }
  __syncthreads();
  if (tid == 0) {
    int off = 0;
    for (int l2 = 0; l2 < 8; ++l2) {
      offs8[l2] = off; cur8[l2] = off;
      off += cnt8[l2] + (cnt8[l2] & 1);
    }
    npS = off >> 1;
  }
  __syncthreads();
  for (int i = tid; i < W; i += 512) {
    const int pos = atomicAdd(&cur8[labw[i]], 1);
    sidx[pos] = (unsigned short)i;
  }
  __syncthreads();
  if (tid < 8 && (cnt8[tid] & 1))
    sidx[offs8[tid] + cnt8[tid]] = sidx[offs8[tid]];   // duplicate-pad odd runs
  __syncthreads();

  const int np = npS;
  const bool act = tid < np;
  int p0 = base, p1 = base, lab = 0;
  float x0[64], x1[64];
  if (act) {
    const int i0 = sidx[2 * tid], i1 = sidx[2 * tid + 1];
    lab = labw[i0];
    p0 = base + i0; p1 = base + i1;
    #pragma unroll
    for (int c = 0; c < 64; ++c) {
      x0[c] = cont[(size_t)c * NPIX + p0];
      x1[c] = cont[(size_t)c * NPIX + p1];
    }
  }

  const float* Tsrc = ws + offT(nblk);
  for (int q = 0; q < 4; ++q) {
    __syncthreads();
    #pragma unroll
    for (int ii = 0; ii < 4; ++ii) {
      const int f = tid + 512 * ii;          // 2048 float4 = 8 labels x 256
      const int ll = f >> 8;
      const int e4 = (f & 255) * 4;
      *reinterpret_cast<float4*>(&Tq[ll * 1028 + e4]) =
          *reinterpret_cast<const float4*>(&Tsrc[(size_t)ll * 4096 + q * 1024 + e4]);
    }
    __syncthreads();
    if (act) {
      const float* Trow = &Tq[lab * 1028];
      #pragma unroll 2
      for (int cc = 0; cc < 16; ++cc) {
        float s0a = 0.f, s0b = 0.f, s1a = 0.f, s1b = 0.f;
        #pragma unroll
        for (int kq = 0; kq < 16; ++kq) {
          const float4 tv = *reinterpret_cast<const float4*>(&Trow[cc * 64 + 4 * kq]);
          s0a += tv.x * x0[4 * kq + 0] + tv.y * x0[4 * kq + 1];
          s0b += tv.z * x0[4 * kq + 2] + tv.w * x0[4 * kq + 3];
          s1a += tv.x * x1[4 * kq + 0] + tv.y * x1[4 * kq + 1];
          s1b += tv.z * x1[4 * kq + 2] + tv.w * x1[4 * kq + 3];
        }
        const int oc = q * 16 + cc;
        const float bs = biasS[lab * 66 + oc];
        out[(size_t)oc * NPIX + p0] = s0a + s0b + bs;
        out[(size_t)oc * NPIX + p1] = s1a + s1b + bs;
      }
    }
  }
}

// =====================================================================
extern "C" void kernel_launch(void* const* d_in, const int* in_sizes, int n_in,
                              void* d_out, int out_size, void* d_ws, size_t ws_size,
                              hipStream_t stream)
{
  const float* cont = (const float*)d_in[0];
  const float* styl = (const float*)d_in[1];
  const int*   cseg = (const int*)d_in[2];
  const int*   sseg = (const int*)d_in[3];
  float*       ws   = (float*)d_ws;
  float*       out  = (float*)d_out;

  const size_t favail = ws_size / 4;
  int nblk = 128;
  while (nblk > 8 && offVALID(nblk) + 8 > favail) nblk >>= 1;

  k_moments<<<dim3(nblk, 2), 512, 0, stream>>>(cont, styl, cseg, sseg, ws, nblk);
  k_reduce<<<dim3(256), 256, 0, stream>>>(ws, nblk);
  k_ns<<<dim3(16), 256, 0, stream>>>(ws, nblk);
  k_tmat<<<dim3(8), 256, 0, stream>>>(ws, nblk);
  k_apply<<<dim3((NPIX + 1007) / 1008), 512, 0, stream>>>(cont, cseg, ws, out, nblk);
}